// Round 10
// baseline (671.944 us; speedup 1.0000x reference)
//
#include <hip/hip_runtime.h>
#include <hip/hip_bf16.h>

#define T_TOK 4096
#define D_MODEL 1024
#define I_DIM 2048
#define E_EXP 16

typedef __bf16 bf16x8 __attribute__((ext_vector_type(8)));
typedef float f32x4 __attribute__((ext_vector_type(4)));

__device__ __forceinline__ bf16x8 pack8(f32x4 a, f32x4 b) {
    bf16x8 r;
    r[0] = (__bf16)a[0]; r[1] = (__bf16)a[1]; r[2] = (__bf16)a[2]; r[3] = (__bf16)a[3];
    r[4] = (__bf16)b[0]; r[5] = (__bf16)b[1]; r[6] = (__bf16)b[2]; r[7] = (__bf16)b[3];
    return r;
}

__device__ __forceinline__ void gl2lds(const __bf16* src, __bf16* dst) {
    __builtin_amdgcn_global_load_lds(
        (const __attribute__((address_space(1))) unsigned int*)src,
        (__attribute__((address_space(3))) unsigned int*)dst, 16, 0, 0);
}

__global__ __launch_bounds__(256) void cvt_kernel(
    const float* __restrict__ in, __bf16* __restrict__ out, int n8)
{
    const int stride = gridDim.x * 256;
    for (int i = blockIdx.x * 256 + threadIdx.x; i < n8; i += stride) {
        f32x4 a = ((const f32x4*)in)[i * 2];
        f32x4 b = ((const f32x4*)in)[i * 2 + 1];
        ((bf16x8*)out)[i] = pack8(a, b);
    }
}

// ---------------- Router phase 1: fp64-accum logits, top-4, softmax-over-top4.
// NO atomics: writes packed expert choices (4x4 bits) + float4 gates per token.
__global__ __launch_bounds__(256) void router_topk_kernel(
    const float* __restrict__ x, const float* __restrict__ rw,
    unsigned int* __restrict__ choices, float* __restrict__ gate4)
{
    const int wid = threadIdx.x >> 6, lane = threadIdx.x & 63;
    const int t = blockIdx.x * 4 + wid;
    const int e = lane & 15, part = lane >> 4;

    const float* xr = x + (size_t)t * D_MODEL + part * 256;
    const float* wr = rw + (size_t)e * D_MODEL + part * 256;
    double acc = 0.0;
    #pragma unroll 4
    for (int i = 0; i < 256; i += 4) {
        f32x4 xv = *(const f32x4*)(xr + i);
        f32x4 wv = *(const f32x4*)(wr + i);
        acc += (double)xv[0] * wv[0] + (double)xv[1] * wv[1]
             + (double)xv[2] * wv[2] + (double)xv[3] * wv[3];
    }
    acc += __shfl_xor(acc, 16, 64);
    acc += __shfl_xor(acc, 32, 64);

    __shared__ float logits[4][16];
    if (lane < 16) logits[wid][lane] = (float)acc;
    __syncthreads();

    if (lane == 0) {
        float l[16];
        #pragma unroll
        for (int i = 0; i < 16; i++) l[i] = logits[wid][i];
        int idx[4]; float val[4];
        unsigned taken = 0;
        for (int k = 0; k < 4; k++) {
            int best = 0; float bv = -1e30f;
            for (int i = 0; i < 16; i++)
                if (!((taken >> i) & 1) && l[i] > bv) { bv = l[i]; best = i; }
            idx[k] = best; val[k] = bv; taken |= (1u << best);
        }
        const float m = val[0];
        float w[4], s = 0.f;
        for (int k = 0; k < 4; k++) { w[k] = __expf(val[k] - m); s += w[k]; }
        choices[t] = (unsigned)idx[0] | ((unsigned)idx[1] << 4)
                   | ((unsigned)idx[2] << 8) | ((unsigned)idx[3] << 12);
        f32x4 g = {w[0] / s, w[1] / s, w[2] / s, w[3] / s};
        *(f32x4*)(gate4 + t * 4) = g;
    }
}

// ---------------- Router phase 2: per-expert list build via ballot prefix sums.
// 16 blocks (one per expert); token-ordered, deterministic, no contended atomics.
__global__ __launch_bounds__(256) void build_lists_kernel(
    const unsigned int* __restrict__ choices, const float* __restrict__ gate4,
    int* __restrict__ counts, int* __restrict__ tok_list, float* __restrict__ gate_list)
{
    const int e = blockIdx.x;
    const int tid = threadIdx.x, lane = tid & 63, w = tid >> 6;
    __shared__ int wave_cnt[4];
    __shared__ int running;
    if (tid == 0) running = 0;
    __syncthreads();
    for (int chunk = 0; chunk < T_TOK; chunk += 256) {
        const int t = chunk + tid;
        const unsigned int ch = choices[t];
        int k = -1;
        #pragma unroll
        for (int kk = 0; kk < 4; ++kk)
            if (((ch >> (4 * kk)) & 15u) == (unsigned)e) k = kk;
        const unsigned long long m = __ballot(k >= 0);
        const int my = __popcll(m & ((1ull << lane) - 1ull));
        if (lane == 0) wave_cnt[w] = __popcll(m);
        __syncthreads();
        int base = running;
        #pragma unroll
        for (int i = 0; i < 4; ++i) if (i < w) base += wave_cnt[i];
        if (k >= 0) {
            const int slot = base + my;
            tok_list[e * T_TOK + slot] = t;
            gate_list[e * T_TOK + slot] = gate4[t * 4 + k];
        }
        __syncthreads();
        if (tid == 0) running += wave_cnt[0] + wave_cnt[1] + wave_cnt[2] + wave_cnt[3];
        __syncthreads();
    }
    if (tid == 0) counts[e] = running;
}

__global__ void prefix_kernel(const int* __restrict__ counts, int* __restrict__ prefix) {
    if (threadIdx.x == 0) {
        int acc = 0;
        for (int e = 0; e < E_EXP; e++) { prefix[e] = acc; acc += (counts[e] + 255) & ~255; }
        prefix[E_EXP] = acc;
    }
}

// ======================= GEMM1 + SwiGLU (m97 structure) =======================
// 128 tok x 64 act-cols (128 B-rows: 64 w1 + 64 v1), BK=64, 4 waves (2Mx2N),
// SINGLE-buffered 32 KB LDS, 2 x __syncthreads per K-step, gl_lds staging.
// 5 blocks/CU (LDS-capacity limit): fill-rate binder scales with residency —
// round-9 PMC showed only ~2 blocks/CU resident at (256,3).
// 16 tileM slots: covers 2048 tokens/expert (counts can exceed 1024!).
__global__ __launch_bounds__(256, 5) void gemm1_kernel(
    const __bf16* __restrict__ xb, const __bf16* __restrict__ wsb,
    const int* __restrict__ counts, const int* __restrict__ prefix,
    const int* __restrict__ tok_list, __bf16* __restrict__ act)
{
    const int q8 = gridDim.x >> 3;                     // 1024
    const int lid = (blockIdx.x & 7) * q8 + (blockIdx.x >> 3);
    const int e = lid >> 9;                            // 512 blocks / expert
    const int r = lid & 511;
    const int tileM = r & 15;                          // 0..15 (2048 tokens)
    const int tileN = r >> 4;                          // 0..31

    const int count = counts[e];
    if (tileM * 128 >= count) return;

    const int tid = threadIdx.x;
    const int lane = tid & 63, w = tid >> 6;
    const int l15 = lane & 15, q = lane >> 4, l7 = lane & 7;
    const int wm = w >> 1, wc = w & 1;

    __shared__ __bf16 As[128 * 64];
    __shared__ __bf16 Bs[128 * 64];

    // staging: wave w covers rows [w*32, w*32+32) of A and of B; 4 issues x 8 rows
    const int rl = lane >> 3;                  // row within 8-row issue group
    const int lc = (lane & 7) ^ rl;            // logical chunk (involution with row&7)
    const __bf16* ptrA[4]; const __bf16* ptrB[4];
    #pragma unroll
    for (int i = 0; i < 4; ++i) {
        int grow = tileM * 128 + w * 32 + i * 8 + rl;
        if (grow >= count) grow = count - 1;
        const int token = tok_list[e * T_TOK + grow];
        ptrA[i] = xb + (size_t)token * D_MODEL + lc * 8;
        const int sub = w * 32 + i * 8 + rl;   // 0..127; rows 0-63 w1, 64-127 v1
        const int gcol = (sub < 64) ? (tileN * 64 + sub) : (I_DIM + tileN * 64 + (sub - 64));
        ptrB[i] = wsb + ((size_t)e * 2 * I_DIM + gcol) * D_MODEL + lc * 8;
    }
    __bf16* dA = &As[w * 2048];
    __bf16* dB = &Bs[w * 2048];

    #define STAGE(koff) do { \
        _Pragma("unroll") \
        for (int i_ = 0; i_ < 4; ++i_) gl2lds(ptrA[i_] + (koff), dA + i_ * 512); \
        _Pragma("unroll") \
        for (int i_ = 0; i_ < 4; ++i_) gl2lds(ptrB[i_] + (koff), dB + i_ * 512); \
    } while (0)

    f32x4 acc[4][4];
    const f32x4 z = {0.f, 0.f, 0.f, 0.f};
    #pragma unroll
    for (int mi = 0; mi < 4; ++mi)
        #pragma unroll
        for (int nj = 0; nj < 4; ++nj) acc[mi][nj] = z;

    const int c0 = (q ^ l7) * 8, c1 = ((4 + q) ^ l7) * 8;
    const int aoff = (wm * 64 + l15) * 64;     // + mi*1024 + c
    const int boff = (wc * 32 + l15) * 64;     // w1: +nj*1024+c ; v1: +4096+nj*1024+c

    STAGE(0);
    for (int kt = 0; kt < 16; ++kt) {
        __syncthreads();                        // drains vmcnt: tile kt resident
        bf16x8 a0[4], a1[4], b0[4], b1[4];
        #pragma unroll
        for (int mi = 0; mi < 4; ++mi) {
            a0[mi] = *(const bf16x8*)&As[aoff + mi * 1024 + c0];
            a1[mi] = *(const bf16x8*)&As[aoff + mi * 1024 + c1];
        }
        #pragma unroll
        for (int nj = 0; nj < 2; ++nj) {
            b0[nj]     = *(const bf16x8*)&Bs[boff + nj * 1024 + c0];
            b0[nj + 2] = *(const bf16x8*)&Bs[boff + 4096 + nj * 1024 + c0];
            b1[nj]     = *(const bf16x8*)&Bs[boff + nj * 1024 + c1];
            b1[nj + 2] = *(const bf16x8*)&Bs[boff + 4096 + nj * 1024 + c1];
        }
        __syncthreads();                        // frags in regs: LDS free to overwrite
        if (kt + 1 < 16) STAGE((kt + 1) * 64);  // loads fly under the MFMAs
        #pragma unroll
        for (int mi = 0; mi < 4; ++mi)
            #pragma unroll
            for (int nj = 0; nj < 4; ++nj) {
                acc[mi][nj] = __builtin_amdgcn_mfma_f32_16x16x32_bf16(a0[mi], b0[nj], acc[mi][nj], 0, 0, 0);
                acc[mi][nj] = __builtin_amdgcn_mfma_f32_16x16x32_bf16(a1[mi], b1[nj], acc[mi][nj], 0, 0, 0);
            }
    }
    #undef STAGE

    const int abase = prefix[e];
    #pragma unroll
    for (int mi = 0; mi < 4; ++mi) {
        #pragma unroll
        for (int j = 0; j < 4; ++j) {
            const int grow = tileM * 128 + wm * 64 + mi * 16 + q * 4 + j;
            if (grow < count) {
                __bf16* arowp = act + (size_t)(abase + grow) * I_DIM + tileN * 64 + wc * 32 + l15;
                #pragma unroll
                for (int nj = 0; nj < 2; ++nj) {
                    const float v1 = acc[mi][nj][j];
                    const float v2 = acc[mi][nj + 2][j];
                    arowp[nj * 16] = (__bf16)(v1 / (1.f + __expf(-v1)) * v2);
                }
            }
        }
    }
}

// ======================= GEMM2 (m97 structure) =======================
// 128 rows x 128 d-cols, K=2048 split in 2 halves (h), BK=64, single-buffer,
// 5 blocks/CU; 16 tileM slots (2048 tokens/expert); atomics scatter gate*y.
__global__ __launch_bounds__(256, 5) void gemm2_kernel(
    const __bf16* __restrict__ act, const __bf16* __restrict__ w2b,
    const int* __restrict__ counts, const int* __restrict__ prefix,
    const int* __restrict__ tok_list, const float* __restrict__ gate_list,
    float* __restrict__ out)
{
    const int q8 = gridDim.x >> 3;                     // 512
    const int lid = (blockIdx.x & 7) * q8 + (blockIdx.x >> 3);
    const int e = lid >> 8;                            // 256 blocks / expert
    const int r = lid & 255;
    const int tileM = r & 15;                          // 0..15
    const int tileN = (r >> 4) & 7;                    // 0..7
    const int h = r >> 7;                              // 0..1

    const int count = counts[e];
    if (tileM * 128 >= count) return;

    const int tid = threadIdx.x;
    const int lane = tid & 63, w = tid >> 6;
    const int l15 = lane & 15, q = lane >> 4, l7 = lane & 7;
    const int wm = w >> 1, wc = w & 1;
    const int abase = prefix[e];

    __shared__ __bf16 As[128 * 64];
    __shared__ __bf16 Bs[128 * 64];

    const int rl = lane >> 3;
    const int lc = (lane & 7) ^ rl;
    const __bf16* ptrA[4]; const __bf16* ptrB[4];
    #pragma unroll
    for (int i = 0; i < 4; ++i) {
        const int ar = tileM * 128 + w * 32 + i * 8 + rl;      // padded rows exist in act
        ptrA[i] = act + (size_t)(abase + ar) * I_DIM + h * 1024 + lc * 8;
        const int dcol = tileN * 128 + w * 32 + i * 8 + rl;
        ptrB[i] = w2b + ((size_t)e * D_MODEL + dcol) * I_DIM + h * 1024 + lc * 8;
    }
    __bf16* dA = &As[w * 2048];
    __bf16* dB = &Bs[w * 2048];

    #define STAGE(koff) do { \
        _Pragma("unroll") \
        for (int i_ = 0; i_ < 4; ++i_) gl2lds(ptrA[i_] + (koff), dA + i_ * 512); \
        _Pragma("unroll") \
        for (int i_ = 0; i_ < 4; ++i_) gl2lds(ptrB[i_] + (koff), dB + i_ * 512); \
    } while (0)

    f32x4 acc[4][4];
    const f32x4 z = {0.f, 0.f, 0.f, 0.f};
    #pragma unroll
    for (int mi = 0; mi < 4; ++mi)
        #pragma unroll
        for (int nj = 0; nj < 4; ++nj) acc[mi][nj] = z;

    const int c0 = (q ^ l7) * 8, c1 = ((4 + q) ^ l7) * 8;
    const int aoff = (wm * 64 + l15) * 64;     // + mi*1024 + c
    const int boff = (wc * 64 + l15) * 64;     // + nj*1024 + c

    STAGE(0);
    for (int kt = 0; kt < 16; ++kt) {
        __syncthreads();
        bf16x8 a0[4], a1[4], b0[4], b1[4];
        #pragma unroll
        for (int mi = 0; mi < 4; ++mi) {
            a0[mi] = *(const bf16x8*)&As[aoff + mi * 1024 + c0];
            a1[mi] = *(const bf16x8*)&As[aoff + mi * 1024 + c1];
        }
        #pragma unroll
        for (int nj = 0; nj < 4; ++nj) {
            b0[nj] = *(const bf16x8*)&Bs[boff + nj * 1024 + c0];
            b1[nj] = *(const bf16x8*)&Bs[boff + nj * 1024 + c1];
        }
        __syncthreads();
        if (kt + 1 < 16) STAGE((kt + 1) * 64);
        #pragma unroll
        for (int mi = 0; mi < 4; ++mi)
            #pragma unroll
            for (int nj = 0; nj < 4; ++nj) {
                acc[mi][nj] = __builtin_amdgcn_mfma_f32_16x16x32_bf16(a0[mi], b0[nj], acc[mi][nj], 0, 0, 0);
                acc[mi][nj] = __builtin_amdgcn_mfma_f32_16x16x32_bf16(a1[mi], b1[nj], acc[mi][nj], 0, 0, 0);
            }
    }
    #undef STAGE

    #pragma unroll
    for (int mi = 0; mi < 4; ++mi) {
        #pragma unroll
        for (int j = 0; j < 4; ++j) {
            const int grow = tileM * 128 + wm * 64 + mi * 16 + q * 4 + j;
            if (grow < count) {
                const int token = tok_list[e * T_TOK + grow];
                const float gate = gate_list[e * T_TOK + grow];
                float* orow = out + (size_t)token * D_MODEL + tileN * 128 + wc * 64 + l15;
                #pragma unroll
                for (int nj = 0; nj < 4; ++nj)
                    atomicAdd(orow + nj * 16, gate * acc[mi][nj][j]);
            }
        }
    }
}

extern "C" void kernel_launch(void* const* d_in, const int* in_sizes, int n_in,
                              void* d_out, int out_size, void* d_ws, size_t ws_size,
                              hipStream_t stream)
{
    const float* x   = (const float*)d_in[0];   // [4096, 1024]
    const float* rw  = (const float*)d_in[1];   // [16, 1024]
    const float* wsw = (const float*)d_in[2];   // [16, 4096, 1024]
    const float* w2s = (const float*)d_in[3];   // [16, 1024, 2048]
    float* out = (float*)d_out;                 // [4096, 1024] fp32

    char* wsb = (char*)d_ws;
    int* counts        = (int*)wsb;                                  // 64 B
    int* prefix        = (int*)(wsb + 128);                          // 17 ints
    int* tok_list      = (int*)(wsb + 1024);                         // 256 KB
    float* gate_list   = (float*)(wsb + 1024 + E_EXP * T_TOK * 4);   // 256 KB
    unsigned* choices  = (unsigned*)(wsb + 544u * 1024);             // 16 KB
    float* gate4       = (float*)(wsb + 576u * 1024);                // 64 KB
    __bf16* x_bf       = (__bf16*)(wsb + (1u << 20));                // [1, 9) MB
    __bf16* act        = (__bf16*)(wsb + (12u << 20));               // [12, ~96) MB (256-padded rows)
    __bf16* ws_bf      = (__bf16*)(wsb + (96u << 20));               // [96, 231) MB
    __bf16* w2_bf      = ws_bf;                                      // aliased: rewritten after gemm1

    hipMemsetAsync(d_out, 0, (size_t)out_size * sizeof(float), stream);

    router_topk_kernel<<<dim3(T_TOK / 4), 256, 0, stream>>>(x, rw, choices, gate4);
    build_lists_kernel<<<dim3(E_EXP), 256, 0, stream>>>(choices, gate4, counts, tok_list, gate_list);
    prefix_kernel<<<1, 64, 0, stream>>>(counts, prefix);

    cvt_kernel<<<2048, 256, 0, stream>>>(x, x_bf, T_TOK * D_MODEL / 8);
    cvt_kernel<<<8192, 256, 0, stream>>>(wsw, ws_bf, E_EXP * 2 * I_DIM * D_MODEL / 8);

    gemm1_kernel<<<dim3(8192), 256, 0, stream>>>(
        x_bf, ws_bf, counts, prefix, tok_list, act);

    cvt_kernel<<<8192, 256, 0, stream>>>(w2s, w2_bf, E_EXP * D_MODEL * I_DIM / 8);

    gemm2_kernel<<<dim3(4096), 256, 0, stream>>>(
        act, w2_bf, counts, prefix, tok_list, gate_list, out);
}

// Round 11
// 502.751 us; speedup vs baseline: 1.3365x; 1.3365x over previous
//
#include <hip/hip_runtime.h>
#include <hip/hip_bf16.h>

#define T_TOK 4096
#define D_MODEL 1024
#define I_DIM 2048
#define E_EXP 16

typedef __bf16 bf16x8 __attribute__((ext_vector_type(8)));
typedef float f32x4 __attribute__((ext_vector_type(4)));

__device__ __forceinline__ bf16x8 pack8(f32x4 a, f32x4 b) {
    bf16x8 r;
    r[0] = (__bf16)a[0]; r[1] = (__bf16)a[1]; r[2] = (__bf16)a[2]; r[3] = (__bf16)a[3];
    r[4] = (__bf16)b[0]; r[5] = (__bf16)b[1]; r[6] = (__bf16)b[2]; r[7] = (__bf16)b[3];
    return r;
}

__device__ __forceinline__ void gl2lds(const __bf16* src, __bf16* dst) {
    __builtin_amdgcn_global_load_lds(
        (const __attribute__((address_space(1))) unsigned int*)src,
        (__attribute__((address_space(3))) unsigned int*)dst, 16, 0, 0);
}

__global__ __launch_bounds__(256) void cvt_kernel(
    const float* __restrict__ in, __bf16* __restrict__ out, int n8)
{
    const int stride = gridDim.x * 256;
    for (int i = blockIdx.x * 256 + threadIdx.x; i < n8; i += stride) {
        f32x4 a = ((const f32x4*)in)[i * 2];
        f32x4 b = ((const f32x4*)in)[i * 2 + 1];
        ((bf16x8*)out)[i] = pack8(a, b);
    }
}

// ---------------- Router phase 1 (FUSED dispatch): blocks 0-1023 do fp64-logit
// top-4 routing (latency-bound, HBM idle); blocks 1024-1279 convert x to bf16;
// blocks 1280-3327 convert ws to bf16 — the 440 MB of cvt streaming rides in
// the router's HBM shadow, removing two serial dispatches. No atomics anywhere.
__global__ __launch_bounds__(256) void router_fused_kernel(
    const float* __restrict__ x, const float* __restrict__ rw,
    unsigned int* __restrict__ choices, float* __restrict__ gate4,
    __bf16* __restrict__ x_bf, const float* __restrict__ wsw, __bf16* __restrict__ ws_bf)
{
    const int b = blockIdx.x;
    if (b >= 1280) {                    // ---- ws cvt: 2048 blocks, 16 iters each
        const int n8 = E_EXP * 2 * I_DIM * D_MODEL / 8;     // 8388608
        for (int i = (b - 1280) * 256 + threadIdx.x; i < n8; i += 2048 * 256) {
            f32x4 a = ((const f32x4*)wsw)[i * 2];
            f32x4 c = ((const f32x4*)wsw)[i * 2 + 1];
            ((bf16x8*)ws_bf)[i] = pack8(a, c);
        }
        return;
    }
    if (b >= 1024) {                    // ---- x cvt: 256 blocks, 8 iters each
        const int n8 = T_TOK * D_MODEL / 8;                 // 524288
        for (int i = (b - 1024) * 256 + threadIdx.x; i < n8; i += 256 * 256) {
            f32x4 a = ((const f32x4*)x)[i * 2];
            f32x4 c = ((const f32x4*)x)[i * 2 + 1];
            ((bf16x8*)x_bf)[i] = pack8(a, c);
        }
        return;
    }
    // ---- router proper: one wave per token
    const int wid = threadIdx.x >> 6, lane = threadIdx.x & 63;
    const int t = b * 4 + wid;
    const int e = lane & 15, part = lane >> 4;

    const float* xr = x + (size_t)t * D_MODEL + part * 256;
    const float* wr = rw + (size_t)e * D_MODEL + part * 256;
    double acc = 0.0;
    #pragma unroll 4
    for (int i = 0; i < 256; i += 4) {
        f32x4 xv = *(const f32x4*)(xr + i);
        f32x4 wv = *(const f32x4*)(wr + i);
        acc += (double)xv[0] * wv[0] + (double)xv[1] * wv[1]
             + (double)xv[2] * wv[2] + (double)xv[3] * wv[3];
    }
    acc += __shfl_xor(acc, 16, 64);
    acc += __shfl_xor(acc, 32, 64);

    __shared__ float logits[4][16];
    if (lane < 16) logits[wid][lane] = (float)acc;
    __syncthreads();

    if (lane == 0) {
        float l[16];
        #pragma unroll
        for (int i = 0; i < 16; i++) l[i] = logits[wid][i];
        int idx[4]; float val[4];
        unsigned taken = 0;
        for (int k = 0; k < 4; k++) {
            int best = 0; float bv = -1e30f;
            for (int i = 0; i < 16; i++)
                if (!((taken >> i) & 1) && l[i] > bv) { bv = l[i]; best = i; }
            idx[k] = best; val[k] = bv; taken |= (1u << best);
        }
        const float m = val[0];
        float w[4], s = 0.f;
        for (int k = 0; k < 4; k++) { w[k] = __expf(val[k] - m); s += w[k]; }
        choices[t] = (unsigned)idx[0] | ((unsigned)idx[1] << 4)
                   | ((unsigned)idx[2] << 8) | ((unsigned)idx[3] << 12);
        f32x4 g = {w[0] / s, w[1] / s, w[2] / s, w[3] / s};
        *(f32x4*)(gate4 + t * 4) = g;
    }
}

// ---------------- Router phase 2: per-expert list build via ballot prefix sums.
// 16 blocks (one per expert); token-ordered, deterministic, no contended atomics.
__global__ __launch_bounds__(256) void build_lists_kernel(
    const unsigned int* __restrict__ choices, const float* __restrict__ gate4,
    int* __restrict__ counts, int* __restrict__ tok_list, float* __restrict__ gate_list)
{
    const int e = blockIdx.x;
    const int tid = threadIdx.x, lane = tid & 63, w = tid >> 6;
    __shared__ int wave_cnt[4];
    __shared__ int running;
    if (tid == 0) running = 0;
    __syncthreads();
    for (int chunk = 0; chunk < T_TOK; chunk += 256) {
        const int t = chunk + tid;
        const unsigned int ch = choices[t];
        int k = -1;
        #pragma unroll
        for (int kk = 0; kk < 4; ++kk)
            if (((ch >> (4 * kk)) & 15u) == (unsigned)e) k = kk;
        const unsigned long long m = __ballot(k >= 0);
        const int my = __popcll(m & ((1ull << lane) - 1ull));
        if (lane == 0) wave_cnt[w] = __popcll(m);
        __syncthreads();
        int base = running;
        #pragma unroll
        for (int i = 0; i < 4; ++i) if (i < w) base += wave_cnt[i];
        if (k >= 0) {
            const int slot = base + my;
            tok_list[e * T_TOK + slot] = t;
            gate_list[e * T_TOK + slot] = gate4[t * 4 + k];
        }
        __syncthreads();
        if (tid == 0) running += wave_cnt[0] + wave_cnt[1] + wave_cnt[2] + wave_cnt[3];
        __syncthreads();
    }
    if (tid == 0) counts[e] = running;
}

__global__ void prefix_kernel(const int* __restrict__ counts, int* __restrict__ prefix) {
    if (threadIdx.x == 0) {
        int acc = 0;
        for (int e = 0; e < E_EXP; e++) { prefix[e] = acc; acc += (counts[e] + 255) & ~255; }
        prefix[E_EXP] = acc;
    }
}

// ======================= GEMM1 + SwiGLU (m97 structure) =======================
// 128 tok x 64 act-cols (128 B-rows: 64 w1 + 64 v1), BK=64, 4 waves (2Mx2N),
// SINGLE-buffered 32 KB LDS, 2 x __syncthreads per K-step, gl_lds staging.
// (256,3): proven point — VGPR 68, no spill. (256,5) forced VGPR 48 < the 64
// the accumulator needs -> 110 MB scratch spill, 300 us (round-10 lesson).
__global__ __launch_bounds__(256, 3) void gemm1_kernel(
    const __bf16* __restrict__ xb, const __bf16* __restrict__ wsb,
    const int* __restrict__ counts, const int* __restrict__ prefix,
    const int* __restrict__ tok_list, __bf16* __restrict__ act)
{
    const int q8 = gridDim.x >> 3;                     // 1024
    const int lid = (blockIdx.x & 7) * q8 + (blockIdx.x >> 3);
    const int e = lid >> 9;                            // 512 blocks / expert
    const int r = lid & 511;
    const int tileM = r & 15;                          // 0..15 (2048 tokens)
    const int tileN = r >> 4;                          // 0..31

    const int count = counts[e];
    if (tileM * 128 >= count) return;

    const int tid = threadIdx.x;
    const int lane = tid & 63, w = tid >> 6;
    const int l15 = lane & 15, q = lane >> 4, l7 = lane & 7;
    const int wm = w >> 1, wc = w & 1;

    __shared__ __bf16 As[128 * 64];
    __shared__ __bf16 Bs[128 * 64];

    // staging: wave w covers rows [w*32, w*32+32) of A and of B; 4 issues x 8 rows
    const int rl = lane >> 3;                  // row within 8-row issue group
    const int lc = (lane & 7) ^ rl;            // logical chunk (involution with row&7)
    const __bf16* ptrA[4]; const __bf16* ptrB[4];
    #pragma unroll
    for (int i = 0; i < 4; ++i) {
        int grow = tileM * 128 + w * 32 + i * 8 + rl;
        if (grow >= count) grow = count - 1;
        const int token = tok_list[e * T_TOK + grow];
        ptrA[i] = xb + (size_t)token * D_MODEL + lc * 8;
        const int sub = w * 32 + i * 8 + rl;   // 0..127; rows 0-63 w1, 64-127 v1
        const int gcol = (sub < 64) ? (tileN * 64 + sub) : (I_DIM + tileN * 64 + (sub - 64));
        ptrB[i] = wsb + ((size_t)e * 2 * I_DIM + gcol) * D_MODEL + lc * 8;
    }
    __bf16* dA = &As[w * 2048];
    __bf16* dB = &Bs[w * 2048];

    #define STAGE(koff) do { \
        _Pragma("unroll") \
        for (int i_ = 0; i_ < 4; ++i_) gl2lds(ptrA[i_] + (koff), dA + i_ * 512); \
        _Pragma("unroll") \
        for (int i_ = 0; i_ < 4; ++i_) gl2lds(ptrB[i_] + (koff), dB + i_ * 512); \
    } while (0)

    f32x4 acc[4][4];
    const f32x4 z = {0.f, 0.f, 0.f, 0.f};
    #pragma unroll
    for (int mi = 0; mi < 4; ++mi)
        #pragma unroll
        for (int nj = 0; nj < 4; ++nj) acc[mi][nj] = z;

    const int c0 = (q ^ l7) * 8, c1 = ((4 + q) ^ l7) * 8;
    const int aoff = (wm * 64 + l15) * 64;     // + mi*1024 + c
    const int boff = (wc * 32 + l15) * 64;     // w1: +nj*1024+c ; v1: +4096+nj*1024+c

    STAGE(0);
    for (int kt = 0; kt < 16; ++kt) {
        __syncthreads();                        // drains vmcnt: tile kt resident
        bf16x8 a0[4], a1[4], b0[4], b1[4];
        #pragma unroll
        for (int mi = 0; mi < 4; ++mi) {
            a0[mi] = *(const bf16x8*)&As[aoff + mi * 1024 + c0];
            a1[mi] = *(const bf16x8*)&As[aoff + mi * 1024 + c1];
        }
        #pragma unroll
        for (int nj = 0; nj < 2; ++nj) {
            b0[nj]     = *(const bf16x8*)&Bs[boff + nj * 1024 + c0];
            b0[nj + 2] = *(const bf16x8*)&Bs[boff + 4096 + nj * 1024 + c0];
            b1[nj]     = *(const bf16x8*)&Bs[boff + nj * 1024 + c1];
            b1[nj + 2] = *(const bf16x8*)&Bs[boff + 4096 + nj * 1024 + c1];
        }
        __syncthreads();                        // frags in regs: LDS free to overwrite
        if (kt + 1 < 16) STAGE((kt + 1) * 64);  // loads fly under the MFMAs
        #pragma unroll
        for (int mi = 0; mi < 4; ++mi)
            #pragma unroll
            for (int nj = 0; nj < 4; ++nj) {
                acc[mi][nj] = __builtin_amdgcn_mfma_f32_16x16x32_bf16(a0[mi], b0[nj], acc[mi][nj], 0, 0, 0);
                acc[mi][nj] = __builtin_amdgcn_mfma_f32_16x16x32_bf16(a1[mi], b1[nj], acc[mi][nj], 0, 0, 0);
            }
    }
    #undef STAGE

    const int abase = prefix[e];
    #pragma unroll
    for (int mi = 0; mi < 4; ++mi) {
        #pragma unroll
        for (int j = 0; j < 4; ++j) {
            const int grow = tileM * 128 + wm * 64 + mi * 16 + q * 4 + j;
            if (grow < count) {
                __bf16* arowp = act + (size_t)(abase + grow) * I_DIM + tileN * 64 + wc * 32 + l15;
                #pragma unroll
                for (int nj = 0; nj < 2; ++nj) {
                    const float v1 = acc[mi][nj][j];
                    const float v2 = acc[mi][nj + 2][j];
                    arowp[nj * 16] = (__bf16)(v1 / (1.f + __expf(-v1)) * v2);
                }
            }
        }
    }
}

// ======================= GEMM2 (m97 structure) =======================
// 128 rows x 128 d-cols, K=2048 split in 2 halves (h), BK=64, single-buffer,
// (256,3); 16 tileM slots (2048 tokens/expert); atomics scatter gate*y.
__global__ __launch_bounds__(256, 3) void gemm2_kernel(
    const __bf16* __restrict__ act, const __bf16* __restrict__ w2b,
    const int* __restrict__ counts, const int* __restrict__ prefix,
    const int* __restrict__ tok_list, const float* __restrict__ gate_list,
    float* __restrict__ out)
{
    const int q8 = gridDim.x >> 3;                     // 512
    const int lid = (blockIdx.x & 7) * q8 + (blockIdx.x >> 3);
    const int e = lid >> 8;                            // 256 blocks / expert
    const int r = lid & 255;
    const int tileM = r & 15;                          // 0..15
    const int tileN = (r >> 4) & 7;                    // 0..7
    const int h = r >> 7;                              // 0..1

    const int count = counts[e];
    if (tileM * 128 >= count) return;

    const int tid = threadIdx.x;
    const int lane = tid & 63, w = tid >> 6;
    const int l15 = lane & 15, q = lane >> 4, l7 = lane & 7;
    const int wm = w >> 1, wc = w & 1;
    const int abase = prefix[e];

    __shared__ __bf16 As[128 * 64];
    __shared__ __bf16 Bs[128 * 64];

    const int rl = lane >> 3;
    const int lc = (lane & 7) ^ rl;
    const __bf16* ptrA[4]; const __bf16* ptrB[4];
    #pragma unroll
    for (int i = 0; i < 4; ++i) {
        const int ar = tileM * 128 + w * 32 + i * 8 + rl;      // padded rows exist in act
        ptrA[i] = act + (size_t)(abase + ar) * I_DIM + h * 1024 + lc * 8;
        const int dcol = tileN * 128 + w * 32 + i * 8 + rl;
        ptrB[i] = w2b + ((size_t)e * D_MODEL + dcol) * I_DIM + h * 1024 + lc * 8;
    }
    __bf16* dA = &As[w * 2048];
    __bf16* dB = &Bs[w * 2048];

    #define STAGE(koff) do { \
        _Pragma("unroll") \
        for (int i_ = 0; i_ < 4; ++i_) gl2lds(ptrA[i_] + (koff), dA + i_ * 512); \
        _Pragma("unroll") \
        for (int i_ = 0; i_ < 4; ++i_) gl2lds(ptrB[i_] + (koff), dB + i_ * 512); \
    } while (0)

    f32x4 acc[4][4];
    const f32x4 z = {0.f, 0.f, 0.f, 0.f};
    #pragma unroll
    for (int mi = 0; mi < 4; ++mi)
        #pragma unroll
        for (int nj = 0; nj < 4; ++nj) acc[mi][nj] = z;

    const int c0 = (q ^ l7) * 8, c1 = ((4 + q) ^ l7) * 8;
    const int aoff = (wm * 64 + l15) * 64;     // + mi*1024 + c
    const int boff = (wc * 64 + l15) * 64;     // + nj*1024 + c

    STAGE(0);
    for (int kt = 0; kt < 16; ++kt) {
        __syncthreads();
        bf16x8 a0[4], a1[4], b0[4], b1[4];
        #pragma unroll
        for (int mi = 0; mi < 4; ++mi) {
            a0[mi] = *(const bf16x8*)&As[aoff + mi * 1024 + c0];
            a1[mi] = *(const bf16x8*)&As[aoff + mi * 1024 + c1];
        }
        #pragma unroll
        for (int nj = 0; nj < 4; ++nj) {
            b0[nj] = *(const bf16x8*)&Bs[boff + nj * 1024 + c0];
            b1[nj] = *(const bf16x8*)&Bs[boff + nj * 1024 + c1];
        }
        __syncthreads();
        if (kt + 1 < 16) STAGE((kt + 1) * 64);
        #pragma unroll
        for (int mi = 0; mi < 4; ++mi)
            #pragma unroll
            for (int nj = 0; nj < 4; ++nj) {
                acc[mi][nj] = __builtin_amdgcn_mfma_f32_16x16x32_bf16(a0[mi], b0[nj], acc[mi][nj], 0, 0, 0);
                acc[mi][nj] = __builtin_amdgcn_mfma_f32_16x16x32_bf16(a1[mi], b1[nj], acc[mi][nj], 0, 0, 0);
            }
    }
    #undef STAGE

    #pragma unroll
    for (int mi = 0; mi < 4; ++mi) {
        #pragma unroll
        for (int j = 0; j < 4; ++j) {
            const int grow = tileM * 128 + wm * 64 + mi * 16 + q * 4 + j;
            if (grow < count) {
                const int token = tok_list[e * T_TOK + grow];
                const float gate = gate_list[e * T_TOK + grow];
                float* orow = out + (size_t)token * D_MODEL + tileN * 128 + wc * 64 + l15;
                #pragma unroll
                for (int nj = 0; nj < 4; ++nj)
                    atomicAdd(orow + nj * 16, gate * acc[mi][nj][j]);
            }
        }
    }
}

extern "C" void kernel_launch(void* const* d_in, const int* in_sizes, int n_in,
                              void* d_out, int out_size, void* d_ws, size_t ws_size,
                              hipStream_t stream)
{
    const float* x   = (const float*)d_in[0];   // [4096, 1024]
    const float* rw  = (const float*)d_in[1];   // [16, 1024]
    const float* wsw = (const float*)d_in[2];   // [16, 4096, 1024]
    const float* w2s = (const float*)d_in[3];   // [16, 1024, 2048]
    float* out = (float*)d_out;                 // [4096, 1024] fp32

    char* wsb = (char*)d_ws;
    int* counts        = (int*)wsb;                                  // 64 B
    int* prefix        = (int*)(wsb + 128);                          // 17 ints
    int* tok_list      = (int*)(wsb + 1024);                         // 256 KB
    float* gate_list   = (float*)(wsb + 1024 + E_EXP * T_TOK * 4);   // 256 KB
    unsigned* choices  = (unsigned*)(wsb + 544u * 1024);             // 16 KB
    float* gate4       = (float*)(wsb + 576u * 1024);                // 64 KB
    __bf16* x_bf       = (__bf16*)(wsb + (1u << 20));                // [1, 9) MB
    __bf16* act        = (__bf16*)(wsb + (12u << 20));               // [12, ~96) MB (256-padded rows)
    __bf16* ws_bf      = (__bf16*)(wsb + (96u << 20));               // [96, 231) MB
    __bf16* w2_bf      = ws_bf;                                      // aliased: rewritten after gemm1

    hipMemsetAsync(d_out, 0, (size_t)out_size * sizeof(float), stream);

    // fused: router (1024 blocks) + x cvt (256) + ws cvt (2048)
    router_fused_kernel<<<dim3(3328), 256, 0, stream>>>(x, rw, choices, gate4, x_bf, wsw, ws_bf);
    build_lists_kernel<<<dim3(E_EXP), 256, 0, stream>>>(choices, gate4, counts, tok_list, gate_list);
    prefix_kernel<<<1, 64, 0, stream>>>(counts, prefix);

    gemm1_kernel<<<dim3(8192), 256, 0, stream>>>(
        x_bf, ws_bf, counts, prefix, tok_list, act);

    cvt_kernel<<<8192, 256, 0, stream>>>(w2s, w2_bf, E_EXP * D_MODEL * I_DIM / 8);

    gemm2_kernel<<<dim3(4096), 256, 0, stream>>>(
        act, w2_bf, counts, prefix, tok_list, gate_list, out);
}

// Round 12
// 443.975 us; speedup vs baseline: 1.5135x; 1.1324x over previous
//
#include <hip/hip_runtime.h>
#include <hip/hip_bf16.h>

#define T_TOK 4096
#define D_MODEL 1024
#define I_DIM 2048
#define E_EXP 16

typedef __bf16 bf16x8 __attribute__((ext_vector_type(8)));
typedef float f32x4 __attribute__((ext_vector_type(4)));

__device__ __forceinline__ bf16x8 pack8(f32x4 a, f32x4 b) {
    bf16x8 r;
    r[0] = (__bf16)a[0]; r[1] = (__bf16)a[1]; r[2] = (__bf16)a[2]; r[3] = (__bf16)a[3];
    r[4] = (__bf16)b[0]; r[5] = (__bf16)b[1]; r[6] = (__bf16)b[2]; r[7] = (__bf16)b[3];
    return r;
}

__device__ __forceinline__ void gl2lds(const __bf16* src, __bf16* dst) {
    __builtin_amdgcn_global_load_lds(
        (const __attribute__((address_space(1))) unsigned int*)src,
        (__attribute__((address_space(3))) unsigned int*)dst, 16, 0, 0);
}

__global__ __launch_bounds__(256) void cvt_kernel(
    const float* __restrict__ in, __bf16* __restrict__ out, int n8)
{
    const int stride = gridDim.x * 256;
    for (int i = blockIdx.x * 256 + threadIdx.x; i < n8; i += stride) {
        f32x4 a = ((const f32x4*)in)[i * 2];
        f32x4 b = ((const f32x4*)in)[i * 2 + 1];
        ((bf16x8*)out)[i] = pack8(a, b);
    }
}

// ---------------- Router phase 1 (FUSED dispatch): blocks 0-1023 do fp64-logit
// top-4 routing; blocks 1024-1279 convert x to bf16; blocks 1280-3327 convert
// ws to bf16 — cvt streaming rides in the router's HBM shadow. No atomics.
__global__ __launch_bounds__(256) void router_fused_kernel(
    const float* __restrict__ x, const float* __restrict__ rw,
    unsigned int* __restrict__ choices, float* __restrict__ gate4,
    __bf16* __restrict__ x_bf, const float* __restrict__ wsw, __bf16* __restrict__ ws_bf)
{
    const int b = blockIdx.x;
    if (b >= 1280) {                    // ---- ws cvt: 2048 blocks
        const int n8 = E_EXP * 2 * I_DIM * D_MODEL / 8;
        for (int i = (b - 1280) * 256 + threadIdx.x; i < n8; i += 2048 * 256) {
            f32x4 a = ((const f32x4*)wsw)[i * 2];
            f32x4 c = ((const f32x4*)wsw)[i * 2 + 1];
            ((bf16x8*)ws_bf)[i] = pack8(a, c);
        }
        return;
    }
    if (b >= 1024) {                    // ---- x cvt: 256 blocks
        const int n8 = T_TOK * D_MODEL / 8;
        for (int i = (b - 1024) * 256 + threadIdx.x; i < n8; i += 256 * 256) {
            f32x4 a = ((const f32x4*)x)[i * 2];
            f32x4 c = ((const f32x4*)x)[i * 2 + 1];
            ((bf16x8*)x_bf)[i] = pack8(a, c);
        }
        return;
    }
    // ---- router proper: one wave per token
    const int wid = threadIdx.x >> 6, lane = threadIdx.x & 63;
    const int t = b * 4 + wid;
    const int e = lane & 15, part = lane >> 4;

    const float* xr = x + (size_t)t * D_MODEL + part * 256;
    const float* wr = rw + (size_t)e * D_MODEL + part * 256;
    double acc = 0.0;
    #pragma unroll 4
    for (int i = 0; i < 256; i += 4) {
        f32x4 xv = *(const f32x4*)(xr + i);
        f32x4 wv = *(const f32x4*)(wr + i);
        acc += (double)xv[0] * wv[0] + (double)xv[1] * wv[1]
             + (double)xv[2] * wv[2] + (double)xv[3] * wv[3];
    }
    acc += __shfl_xor(acc, 16, 64);
    acc += __shfl_xor(acc, 32, 64);

    __shared__ float logits[4][16];
    if (lane < 16) logits[wid][lane] = (float)acc;
    __syncthreads();

    if (lane == 0) {
        float l[16];
        #pragma unroll
        for (int i = 0; i < 16; i++) l[i] = logits[wid][i];
        int idx[4]; float val[4];
        unsigned taken = 0;
        for (int k = 0; k < 4; k++) {
            int best = 0; float bv = -1e30f;
            for (int i = 0; i < 16; i++)
                if (!((taken >> i) & 1) && l[i] > bv) { bv = l[i]; best = i; }
            idx[k] = best; val[k] = bv; taken |= (1u << best);
        }
        const float m = val[0];
        float w[4], s = 0.f;
        for (int k = 0; k < 4; k++) { w[k] = __expf(val[k] - m); s += w[k]; }
        choices[t] = (unsigned)idx[0] | ((unsigned)idx[1] << 4)
                   | ((unsigned)idx[2] << 8) | ((unsigned)idx[3] << 12);
        f32x4 g = {w[0] / s, w[1] / s, w[2] / s, w[3] / s};
        *(f32x4*)(gate4 + t * 4) = g;
    }
}

// ---------------- Router phase 2: per-expert lists via ballot prefix sums.
// Also records kidx (which of the token's 4 choices this expert is) so gemm2
// can scatter partials deterministically without atomics.
__global__ __launch_bounds__(256) void build_lists_kernel(
    const unsigned int* __restrict__ choices, const float* __restrict__ gate4,
    int* __restrict__ counts, int* __restrict__ tok_list, float* __restrict__ gate_list,
    int* __restrict__ kidx_list)
{
    const int e = blockIdx.x;
    const int tid = threadIdx.x, lane = tid & 63, w = tid >> 6;
    __shared__ int wave_cnt[4];
    __shared__ int running;
    if (tid == 0) running = 0;
    __syncthreads();
    for (int chunk = 0; chunk < T_TOK; chunk += 256) {
        const int t = chunk + tid;
        const unsigned int ch = choices[t];
        int k = -1;
        #pragma unroll
        for (int kk = 0; kk < 4; ++kk)
            if (((ch >> (4 * kk)) & 15u) == (unsigned)e) k = kk;
        const unsigned long long m = __ballot(k >= 0);
        const int my = __popcll(m & ((1ull << lane) - 1ull));
        if (lane == 0) wave_cnt[w] = __popcll(m);
        __syncthreads();
        int base = running;
        #pragma unroll
        for (int i = 0; i < 4; ++i) if (i < w) base += wave_cnt[i];
        if (k >= 0) {
            const int slot = base + my;
            tok_list[e * T_TOK + slot] = t;
            gate_list[e * T_TOK + slot] = gate4[t * 4 + k];
            kidx_list[e * T_TOK + slot] = k;
        }
        __syncthreads();
        if (tid == 0) running += wave_cnt[0] + wave_cnt[1] + wave_cnt[2] + wave_cnt[3];
        __syncthreads();
    }
    if (tid == 0) counts[e] = running;
}

__global__ void prefix_kernel(const int* __restrict__ counts, int* __restrict__ prefix) {
    if (threadIdx.x == 0) {
        int acc = 0;
        for (int e = 0; e < E_EXP; e++) { prefix[e] = acc; acc += (counts[e] + 255) & ~255; }
        prefix[E_EXP] = acc;
    }
}

// ======================= GEMM1 + SwiGLU (m97 structure, unchanged) ============
__global__ __launch_bounds__(256, 3) void gemm1_kernel(
    const __bf16* __restrict__ xb, const __bf16* __restrict__ wsb,
    const int* __restrict__ counts, const int* __restrict__ prefix,
    const int* __restrict__ tok_list, __bf16* __restrict__ act)
{
    const int q8 = gridDim.x >> 3;                     // 1024
    const int lid = (blockIdx.x & 7) * q8 + (blockIdx.x >> 3);
    const int e = lid >> 9;                            // 512 blocks / expert
    const int r = lid & 511;
    const int tileM = r & 15;                          // 0..15 (2048 tokens)
    const int tileN = r >> 4;                          // 0..31

    const int count = counts[e];
    if (tileM * 128 >= count) return;

    const int tid = threadIdx.x;
    const int lane = tid & 63, w = tid >> 6;
    const int l15 = lane & 15, q = lane >> 4, l7 = lane & 7;
    const int wm = w >> 1, wc = w & 1;

    __shared__ __bf16 As[128 * 64];
    __shared__ __bf16 Bs[128 * 64];

    const int rl = lane >> 3;
    const int lc = (lane & 7) ^ rl;
    const __bf16* ptrA[4]; const __bf16* ptrB[4];
    #pragma unroll
    for (int i = 0; i < 4; ++i) {
        int grow = tileM * 128 + w * 32 + i * 8 + rl;
        if (grow >= count) grow = count - 1;
        const int token = tok_list[e * T_TOK + grow];
        ptrA[i] = xb + (size_t)token * D_MODEL + lc * 8;
        const int sub = w * 32 + i * 8 + rl;
        const int gcol = (sub < 64) ? (tileN * 64 + sub) : (I_DIM + tileN * 64 + (sub - 64));
        ptrB[i] = wsb + ((size_t)e * 2 * I_DIM + gcol) * D_MODEL + lc * 8;
    }
    __bf16* dA = &As[w * 2048];
    __bf16* dB = &Bs[w * 2048];

    #define STAGE(koff) do { \
        _Pragma("unroll") \
        for (int i_ = 0; i_ < 4; ++i_) gl2lds(ptrA[i_] + (koff), dA + i_ * 512); \
        _Pragma("unroll") \
        for (int i_ = 0; i_ < 4; ++i_) gl2lds(ptrB[i_] + (koff), dB + i_ * 512); \
    } while (0)

    f32x4 acc[4][4];
    const f32x4 z = {0.f, 0.f, 0.f, 0.f};
    #pragma unroll
    for (int mi = 0; mi < 4; ++mi)
        #pragma unroll
        for (int nj = 0; nj < 4; ++nj) acc[mi][nj] = z;

    const int c0 = (q ^ l7) * 8, c1 = ((4 + q) ^ l7) * 8;
    const int aoff = (wm * 64 + l15) * 64;
    const int boff = (wc * 32 + l15) * 64;

    STAGE(0);
    for (int kt = 0; kt < 16; ++kt) {
        __syncthreads();
        bf16x8 a0[4], a1[4], b0[4], b1[4];
        #pragma unroll
        for (int mi = 0; mi < 4; ++mi) {
            a0[mi] = *(const bf16x8*)&As[aoff + mi * 1024 + c0];
            a1[mi] = *(const bf16x8*)&As[aoff + mi * 1024 + c1];
        }
        #pragma unroll
        for (int nj = 0; nj < 2; ++nj) {
            b0[nj]     = *(const bf16x8*)&Bs[boff + nj * 1024 + c0];
            b0[nj + 2] = *(const bf16x8*)&Bs[boff + 4096 + nj * 1024 + c0];
            b1[nj]     = *(const bf16x8*)&Bs[boff + nj * 1024 + c1];
            b1[nj + 2] = *(const bf16x8*)&Bs[boff + 4096 + nj * 1024 + c1];
        }
        __syncthreads();
        if (kt + 1 < 16) STAGE((kt + 1) * 64);
        #pragma unroll
        for (int mi = 0; mi < 4; ++mi)
            #pragma unroll
            for (int nj = 0; nj < 4; ++nj) {
                acc[mi][nj] = __builtin_amdgcn_mfma_f32_16x16x32_bf16(a0[mi], b0[nj], acc[mi][nj], 0, 0, 0);
                acc[mi][nj] = __builtin_amdgcn_mfma_f32_16x16x32_bf16(a1[mi], b1[nj], acc[mi][nj], 0, 0, 0);
            }
    }
    #undef STAGE

    const int abase = prefix[e];
    #pragma unroll
    for (int mi = 0; mi < 4; ++mi) {
        #pragma unroll
        for (int j = 0; j < 4; ++j) {
            const int grow = tileM * 128 + wm * 64 + mi * 16 + q * 4 + j;
            if (grow < count) {
                __bf16* arowp = act + (size_t)(abase + grow) * I_DIM + tileN * 64 + wc * 32 + l15;
                #pragma unroll
                for (int nj = 0; nj < 2; ++nj) {
                    const float v1 = acc[mi][nj][j];
                    const float v2 = acc[mi][nj + 2][j];
                    arowp[nj * 16] = (__bf16)(v1 / (1.f + __expf(-v1)) * v2);
                }
            }
        }
    }
}

// ======================= GEMM2 (atomic-free) =======================
// 128 rows x 128 d-cols, FULL K=2048 (32 K-steps), single-buffer, (256,3).
// Epilogue: PLAIN stores of gate*y into ypart[(token*4+kidx)*1024+d] — each
// cell written exactly once (deterministic); combine_kernel sums the 4.
__global__ __launch_bounds__(256, 3) void gemm2_kernel(
    const __bf16* __restrict__ act, const __bf16* __restrict__ w2b,
    const int* __restrict__ counts, const int* __restrict__ prefix,
    const int* __restrict__ tok_list, const float* __restrict__ gate_list,
    const int* __restrict__ kidx_list, float* __restrict__ ypart)
{
    const int q8 = gridDim.x >> 3;                     // 256
    const int lid = (blockIdx.x & 7) * q8 + (blockIdx.x >> 3);
    const int e = lid >> 7;                            // 128 blocks / expert
    const int r = lid & 127;
    const int tileM = r & 15;                          // 0..15
    const int tileN = r >> 4;                          // 0..7

    const int count = counts[e];
    if (tileM * 128 >= count) return;

    const int tid = threadIdx.x;
    const int lane = tid & 63, w = tid >> 6;
    const int l15 = lane & 15, q = lane >> 4, l7 = lane & 7;
    const int wm = w >> 1, wc = w & 1;
    const int abase = prefix[e];

    __shared__ __bf16 As[128 * 64];
    __shared__ __bf16 Bs[128 * 64];

    const int rl = lane >> 3;
    const int lc = (lane & 7) ^ rl;
    const __bf16* ptrA[4]; const __bf16* ptrB[4];
    #pragma unroll
    for (int i = 0; i < 4; ++i) {
        const int ar = tileM * 128 + w * 32 + i * 8 + rl;      // padded rows exist in act
        ptrA[i] = act + (size_t)(abase + ar) * I_DIM + lc * 8;
        const int dcol = tileN * 128 + w * 32 + i * 8 + rl;
        ptrB[i] = w2b + ((size_t)e * D_MODEL + dcol) * I_DIM + lc * 8;
    }
    __bf16* dA = &As[w * 2048];
    __bf16* dB = &Bs[w * 2048];

    #define STAGE(koff) do { \
        _Pragma("unroll") \
        for (int i_ = 0; i_ < 4; ++i_) gl2lds(ptrA[i_] + (koff), dA + i_ * 512); \
        _Pragma("unroll") \
        for (int i_ = 0; i_ < 4; ++i_) gl2lds(ptrB[i_] + (koff), dB + i_ * 512); \
    } while (0)

    f32x4 acc[4][4];
    const f32x4 z = {0.f, 0.f, 0.f, 0.f};
    #pragma unroll
    for (int mi = 0; mi < 4; ++mi)
        #pragma unroll
        for (int nj = 0; nj < 4; ++nj) acc[mi][nj] = z;

    const int c0 = (q ^ l7) * 8, c1 = ((4 + q) ^ l7) * 8;
    const int aoff = (wm * 64 + l15) * 64;
    const int boff = (wc * 64 + l15) * 64;

    STAGE(0);
    for (int kt = 0; kt < 32; ++kt) {
        __syncthreads();
        bf16x8 a0[4], a1[4], b0[4], b1[4];
        #pragma unroll
        for (int mi = 0; mi < 4; ++mi) {
            a0[mi] = *(const bf16x8*)&As[aoff + mi * 1024 + c0];
            a1[mi] = *(const bf16x8*)&As[aoff + mi * 1024 + c1];
        }
        #pragma unroll
        for (int nj = 0; nj < 4; ++nj) {
            b0[nj] = *(const bf16x8*)&Bs[boff + nj * 1024 + c0];
            b1[nj] = *(const bf16x8*)&Bs[boff + nj * 1024 + c1];
        }
        __syncthreads();
        if (kt + 1 < 32) STAGE((kt + 1) * 64);
        #pragma unroll
        for (int mi = 0; mi < 4; ++mi)
            #pragma unroll
            for (int nj = 0; nj < 4; ++nj) {
                acc[mi][nj] = __builtin_amdgcn_mfma_f32_16x16x32_bf16(a0[mi], b0[nj], acc[mi][nj], 0, 0, 0);
                acc[mi][nj] = __builtin_amdgcn_mfma_f32_16x16x32_bf16(a1[mi], b1[nj], acc[mi][nj], 0, 0, 0);
            }
    }
    #undef STAGE

    #pragma unroll
    for (int mi = 0; mi < 4; ++mi) {
        #pragma unroll
        for (int j = 0; j < 4; ++j) {
            const int grow = tileM * 128 + wm * 64 + mi * 16 + q * 4 + j;
            if (grow < count) {
                const int token = tok_list[e * T_TOK + grow];
                const int kk = kidx_list[e * T_TOK + grow];
                const float gate = gate_list[e * T_TOK + grow];
                float* orow = ypart + ((size_t)token * 4 + kk) * D_MODEL + tileN * 128 + wc * 64 + l15;
                #pragma unroll
                for (int nj = 0; nj < 4; ++nj)
                    orow[nj * 16] = gate * acc[mi][nj][j];
            }
        }
    }
}

// ---------------- Combine: out[t] = sum of the token's 4 gated partials ------
__global__ __launch_bounds__(256) void combine_kernel(
    const float* __restrict__ ypart, float* __restrict__ out)
{
    const int t = blockIdx.x;
    const int d = threadIdx.x * 4;
    const float* p = ypart + (size_t)t * 4 * D_MODEL;
    f32x4 s = *(const f32x4*)(p + d);
    s += *(const f32x4*)(p + D_MODEL + d);
    s += *(const f32x4*)(p + 2 * D_MODEL + d);
    s += *(const f32x4*)(p + 3 * D_MODEL + d);
    *(f32x4*)(out + (size_t)t * D_MODEL + d) = s;
}

extern "C" void kernel_launch(void* const* d_in, const int* in_sizes, int n_in,
                              void* d_out, int out_size, void* d_ws, size_t ws_size,
                              hipStream_t stream)
{
    const float* x   = (const float*)d_in[0];   // [4096, 1024]
    const float* rw  = (const float*)d_in[1];   // [16, 1024]
    const float* wsw = (const float*)d_in[2];   // [16, 4096, 1024]
    const float* w2s = (const float*)d_in[3];   // [16, 1024, 2048]
    float* out = (float*)d_out;                 // [4096, 1024] fp32

    char* wsb = (char*)d_ws;
    int* counts        = (int*)wsb;                                  // 64 B
    int* prefix        = (int*)(wsb + 128);                          // 17 ints
    int* tok_list      = (int*)(wsb + 1024);                         // 256 KB
    float* gate_list   = (float*)(wsb + 1024 + E_EXP * T_TOK * 4);   // 256 KB
    unsigned* choices  = (unsigned*)(wsb + 544u * 1024);             // 16 KB
    float* gate4       = (float*)(wsb + 576u * 1024);                // 64 KB
    int* kidx_list     = (int*)(wsb + 640u * 1024);                  // 256 KB
    __bf16* x_bf       = (__bf16*)(wsb + (1u << 20));                // [1, 9) MB
    __bf16* act        = (__bf16*)(wsb + (12u << 20));               // [12, 96) MB (256-padded rows)
    __bf16* ws_bf      = (__bf16*)(wsb + (96u << 20));               // [96, 230) MB — dead after gemm1
    __bf16* w2_bf      = ws_bf;                                      // [96, 160) MB, written after gemm1
    float* ypart       = (float*)(wsb + (160u << 20));               // [160, 227) MB, written after cvt_w2

    // fused: router (1024 blocks) + x cvt (256) + ws cvt (2048)
    router_fused_kernel<<<dim3(3328), 256, 0, stream>>>(x, rw, choices, gate4, x_bf, wsw, ws_bf);
    build_lists_kernel<<<dim3(E_EXP), 256, 0, stream>>>(choices, gate4, counts, tok_list, gate_list, kidx_list);
    prefix_kernel<<<1, 64, 0, stream>>>(counts, prefix);

    gemm1_kernel<<<dim3(8192), 256, 0, stream>>>(
        x_bf, ws_bf, counts, prefix, tok_list, act);

    cvt_kernel<<<8192, 256, 0, stream>>>(w2s, w2_bf, E_EXP * D_MODEL * I_DIM / 8);

    gemm2_kernel<<<dim3(2048), 256, 0, stream>>>(
        act, w2_bf, counts, prefix, tok_list, gate_list, kidx_list, ypart);

    combine_kernel<<<dim3(T_TOK), 256, 0, stream>>>(ypart, out);
}